// Round 14
// baseline (286.218 us; speedup 1.0000x reference)
//
#include <hip/hip_runtime.h>
#include <hip/hip_bf16.h>
#include <math.h>

#define N_NODES 50000
#define N_EDGES 800000
#define IN_F    128
#define HID     128
#define CLS     32
#define NHEAD   4
#define NBUCK   196        // ceil(N_NODES / 256)

typedef __attribute__((ext_vector_type(8))) short  short8;
typedef __attribute__((ext_vector_type(4))) float  floatx4;
typedef __attribute__((ext_vector_type(2))) float  f32x2;
typedef _Float16 h2 __attribute__((ext_vector_type(2)));

// ---------- conversions ----------
static __device__ __forceinline__ unsigned short f2bf(float f) {
    unsigned int u = __float_as_uint(f);
    return (unsigned short)((u + 0x7fffu + ((u >> 16) & 1u)) >> 16);
}
static __device__ __forceinline__ unsigned short f2h(float f) {
    return __builtin_bit_cast(unsigned short, (_Float16)f);
}
static __device__ __forceinline__ h2 uh2(unsigned int u) {
    return __builtin_bit_cast(h2, u);
}
static __device__ __forceinline__ float elu1(float x) {
    return x > 0.f ? x : expm1f(x);
}

// fp8 8-elem dot against f32 q: two chains for ILP
static __device__ __forceinline__ float dot8f8(const float* qf, uint2 kw) {
    f32x2 a0 = __builtin_amdgcn_cvt_pk_f32_fp8((int)kw.x, false);
    f32x2 a1 = __builtin_amdgcn_cvt_pk_f32_fp8((int)kw.x, true);
    f32x2 a2 = __builtin_amdgcn_cvt_pk_f32_fp8((int)kw.y, false);
    f32x2 a3 = __builtin_amdgcn_cvt_pk_f32_fp8((int)kw.y, true);
    float p0 = fmaf(qf[0], a0.x, qf[1] * a0.y);
    p0 = fmaf(qf[2], a1.x, fmaf(qf[3], a1.y, p0));
    float p1 = fmaf(qf[4], a2.x, qf[5] * a2.y);
    p1 = fmaf(qf[6], a3.x, fmaf(qf[7], a3.y, p1));
    return p0 + p1;
}
static __device__ __forceinline__ void acc8f8(float* ax, float e, uint2 vw) {
    f32x2 a0 = __builtin_amdgcn_cvt_pk_f32_fp8((int)vw.x, false);
    f32x2 a1 = __builtin_amdgcn_cvt_pk_f32_fp8((int)vw.x, true);
    f32x2 a2 = __builtin_amdgcn_cvt_pk_f32_fp8((int)vw.y, false);
    f32x2 a3 = __builtin_amdgcn_cvt_pk_f32_fp8((int)vw.y, true);
    ax[0] = fmaf(e, a0.x, ax[0]); ax[1] = fmaf(e, a0.y, ax[1]);
    ax[2] = fmaf(e, a1.x, ax[2]); ax[3] = fmaf(e, a1.y, ax[3]);
    ax[4] = fmaf(e, a2.x, ax[4]); ax[5] = fmaf(e, a2.y, ax[5]);
    ax[6] = fmaf(e, a3.x, ax[6]); ax[7] = fmaf(e, a3.y, ax[7]);
}
static __device__ __forceinline__ void load_qf(const unsigned short* qp, float* qf) {
    uint4 qw = *(const uint4*)qp;
    h2 t0 = uh2(qw.x), t1 = uh2(qw.y), t2 = uh2(qw.z), t3 = uh2(qw.w);
    qf[0] = (float)t0.x; qf[1] = (float)t0.y;
    qf[2] = (float)t1.x; qf[3] = (float)t1.y;
    qf[4] = (float)t2.x; qf[5] = (float)t2.y;
    qf[6] = (float)t3.x; qf[7] = (float)t3.y;
}

// ---------- weight conversion: all 6 matrices in one launch ----------
__global__ __launch_bounds__(256) void conv6(
    const float* __restrict__ a0, const float* __restrict__ a1, const float* __restrict__ a2,
    const float* __restrict__ a3, const float* __restrict__ a4, const float* __restrict__ a5,
    unsigned short* __restrict__ o0, unsigned short* __restrict__ o1, unsigned short* __restrict__ o2,
    unsigned short* __restrict__ o3, unsigned short* __restrict__ o4, unsigned short* __restrict__ o5,
    int cBig, int cSmall)
{
    const float* srcs[6] = {a0, a1, a2, a3, a4, a5};
    unsigned short* dsts[6] = {o0, o1, o2, o3, o4, o5};
    int s = blockIdx.y;
    int count = (s < 3) ? cBig : cSmall;
    int i = blockIdx.x * 256 + threadIdx.x;
    if (i < count) dsts[s][i] = f2bf(srcs[s][i]);
}

// ================= CSR build: 2-pass coarse-bucket counting sort =================
__global__ __launch_bounds__(256) void bucket_hist(
    const int* __restrict__ e0, const int* __restrict__ e1,
    const int* __restrict__ e2, const int* __restrict__ e3,
    int* __restrict__ bcnt, int nE)
{
    const int s = blockIdx.y;
    const int* ep = (s == 0) ? e0 : (s == 1) ? e1 : (s == 2) ? e2 : e3;
    __shared__ int h[NBUCK];
    for (int i = threadIdx.x; i < NBUCK; i += 256) h[i] = 0;
    __syncthreads();
    for (int e = blockIdx.x * 256 + threadIdx.x; e < nE; e += gridDim.x * 256)
        atomicAdd(&h[ep[e] >> 8], 1);
    __syncthreads();
    for (int i = threadIdx.x; i < NBUCK; i += 256)
        if (h[i]) atomicAdd(&bcnt[s * NBUCK + i], h[i]);
}

__global__ __launch_bounds__(256) void bucket_scan(
    const int* __restrict__ bcnt, int* __restrict__ bbase, int* __restrict__ bcur)
{
    int s = blockIdx.x;
    __shared__ int tmp[256];
    int v = (threadIdx.x < NBUCK) ? bcnt[s * NBUCK + threadIdx.x] : 0;
    tmp[threadIdx.x] = v; __syncthreads();
    for (int o = 1; o < 256; o <<= 1) {
        int t = (threadIdx.x >= o) ? tmp[threadIdx.x - o] : 0;
        __syncthreads(); tmp[threadIdx.x] += t; __syncthreads();
    }
    int excl = tmp[threadIdx.x] - v;
    if (threadIdx.x < NBUCK) {
        bbase[s * (NBUCK + 1) + threadIdx.x] = excl;
        bcur[s * NBUCK + threadIdx.x] = excl;
    }
    if (threadIdx.x == NBUCK - 1)
        bbase[s * (NBUCK + 1) + NBUCK] = excl + v;
}

// pass 1: packed (src&255)<<16 | dst  (dst < 65536 since N=50000)
#define TILE 8192
__global__ __launch_bounds__(256) void pass1_scatter(
    const int* __restrict__ e0, const int* __restrict__ e1,
    const int* __restrict__ e2, const int* __restrict__ e3,
    int* __restrict__ bcur, unsigned int* __restrict__ pairs, int nE)
{
    const int s = blockIdx.y;
    const int* ep = (s == 0) ? e0 : (s == 1) ? e1 : (s == 2) ? e2 : e3;
    const int tile0 = blockIdx.x * TILE;
    __shared__ int hist[NBUCK], base[NBUCK], cur[NBUCK];
    for (int i = threadIdx.x; i < NBUCK; i += 256) { hist[i] = 0; cur[i] = 0; }
    __syncthreads();
    for (int i = threadIdx.x; i < TILE; i += 256) {
        int e = tile0 + i;
        if (e < nE) atomicAdd(&hist[ep[e] >> 8], 1);
    }
    __syncthreads();
    for (int i = threadIdx.x; i < NBUCK; i += 256)
        base[i] = hist[i] ? atomicAdd(&bcur[s * NBUCK + i], hist[i]) : 0;
    __syncthreads();
    unsigned int* pp = pairs + (size_t)s * nE;
    for (int i = threadIdx.x; i < TILE; i += 256) {
        int e = tile0 + i;
        if (e < nE) {
            int src = ep[e], dst = ep[e + nE];
            int b = src >> 8;
            int r = atomicAdd(&cur[b], 1);
            pp[base[b] + r] = ((unsigned int)(src & 255) << 16) | (unsigned int)dst;
        }
    }
}

__global__ __launch_bounds__(256) void pass2_place(
    const unsigned int* __restrict__ pairs, const int* __restrict__ bbase,
    int* __restrict__ rowptr, int* __restrict__ deg, int* __restrict__ col,
    int nE, int n)
{
    const int s = blockIdx.y, b = blockIdx.x;
    const int base0 = bbase[s * (NBUCK + 1) + b];
    const int ecnt  = bbase[s * (NBUCK + 1) + b + 1] - base0;
    const unsigned int* pp = pairs + (size_t)s * nE + base0;
    __shared__ int hist[256], cur[256];
    hist[threadIdx.x] = 0;
    __syncthreads();
    for (int i = threadIdx.x; i < ecnt; i += 256)
        atomicAdd(&hist[(pp[i] >> 16) & 255], 1);
    __syncthreads();
    int v = hist[threadIdx.x];
    cur[threadIdx.x] = v; __syncthreads();
    for (int o = 1; o < 256; o <<= 1) {
        int t = (threadIdx.x >= o) ? cur[threadIdx.x - o] : 0;
        __syncthreads(); cur[threadIdx.x] += t; __syncthreads();
    }
    int excl = cur[threadIdx.x] - v;
    int node = b * 256 + threadIdx.x;
    if (node < n) {
        rowptr[(size_t)s * n + node] = base0 + excl;
        deg[(size_t)s * n + node] = v;
    }
    __syncthreads();
    cur[threadIdx.x] = excl;
    __syncthreads();
    int* colp = col + (size_t)s * nE + base0;
    for (int i = threadIdx.x; i < ecnt; i += 256) {
        unsigned int pr = pp[i];
        int r = atomicAdd(&cur[(pr >> 16) & 255], 1);
        colp[r] = (int)(pr & 0xffffu);
    }
}

// ================= LDS-tiled MFMA Q/K/V projection ============================
static __device__ __forceinline__ short8 pack8(const float* p) {
    float4 a = *(const float4*)p;
    float4 b = *(const float4*)(p + 4);
    short8 v;
    v[0] = (short)f2bf(a.x); v[1] = (short)f2bf(a.y);
    v[2] = (short)f2bf(a.z); v[3] = (short)f2bf(a.w);
    v[4] = (short)f2bf(b.x); v[5] = (short)f2bf(b.y);
    v[6] = (short)f2bf(b.z); v[7] = (short)f2bf(b.w);
    return v;
}

template<int A, bool KV8>
__global__ __launch_bounds__(256) void qkv_lds(
    const float* __restrict__ x,
    const unsigned short* __restrict__ Wq, const float* __restrict__ bq,
    const unsigned short* __restrict__ Wk, const float* __restrict__ bk,
    const unsigned short* __restrict__ Wv, const float* __restrict__ bv,
    unsigned short* __restrict__ q0, unsigned short* __restrict__ q1,
    void* __restrict__ k0, void* __restrict__ k1,
    void* __restrict__ v0, void* __restrict__ v1,
    int n)
{
    constexpr int NT   = A / 16;
    constexpr int WROW = IN_F + 8;
    constexpr int OROW = A + 8;
    __shared__ unsigned short Wb[A * WROW];
    __shared__ unsigned short Ob[64 * OROW];

    const int t    = threadIdx.x;
    const int wave = t >> 6;
    const int lane = t & 63;
    const int r    = lane & 15;
    const int kg   = lane >> 4;
    const int node0 = blockIdx.x * 64;
    const int myrow = wave * 16 + r;
    const int xnode = min(node0 + myrow, n - 1);

    short8 xf[4];
    const float* xr = x + (unsigned)xnode * IN_F + kg * 8;
#pragma unroll
    for (int ks = 0; ks < 4; ++ks) xf[ks] = pack8(xr + ks * 32);

    const size_t off = (size_t)A * IN_F;
    const unsigned short* Ws[6] = {Wq, Wk, Wv, Wq + off, Wk + off, Wv + off};
    const float*          bs[6] = {bq, bk, bv, bq + A, bk + A, bv + A};
    void*                 os[6] = {q0, k0, v0, q1, k1, v1};

    for (int s = 0; s < 6; ++s) {
        const unsigned short* Wg = Ws[s];
#pragma unroll
        for (int it = 0; it < A * IN_F / 2048; ++it) {
            int e = (it * 256 + t) * 8;
            int row = e / IN_F, c = e % IN_F;
            *(uint4*)&Wb[row * WROW + c] = *(const uint4*)&Wg[e];
        }
        __syncthreads();

        floatx4 acc[NT];
        const float* b = bs[s];
#pragma unroll
        for (int nt = 0; nt < NT; ++nt) {
            float4 b4 = *(const float4*)(b + nt * 16 + kg * 4);
            acc[nt] = (floatx4){b4.x, b4.y, b4.z, b4.w};
        }
#pragma unroll
        for (int ks = 0; ks < 4; ++ks) {
#pragma unroll
            for (int nt = 0; nt < NT; ++nt) {
                short8 wf = *(const short8*)&Wb[(nt * 16 + r) * WROW + ks * 32 + kg * 8];
                acc[nt] = __builtin_amdgcn_mfma_f32_16x16x32_bf16(wf, xf[ks], acc[nt], 0, 0, 0);
            }
        }

        const bool f8 = KV8 && (s != 0) && (s != 3);
        if (f8) {
            unsigned char* Obb = (unsigned char*)Ob;
#pragma unroll
            for (int nt = 0; nt < NT; ++nt) {
                int p = __builtin_amdgcn_cvt_pk_fp8_f32(acc[nt][0], acc[nt][1], 0, false);
                p     = __builtin_amdgcn_cvt_pk_fp8_f32(acc[nt][2], acc[nt][3], p, true);
                *(unsigned int*)&Obb[myrow * OROW + nt * 16 + kg * 4] = (unsigned int)p;
            }
        } else {
#pragma unroll
            for (int nt = 0; nt < NT; ++nt) {
                unsigned int lo = (unsigned int)f2h(acc[nt][0]) | ((unsigned int)f2h(acc[nt][1]) << 16);
                unsigned int hi = (unsigned int)f2h(acc[nt][2]) | ((unsigned int)f2h(acc[nt][3]) << 16);
                *(uint2*)&Ob[myrow * OROW + nt * 16 + kg * 4] = make_uint2(lo, hi);
            }
        }
        __syncthreads();

        if (f8) {
            const unsigned char* Obb = (const unsigned char*)Ob;
            unsigned char* og = (unsigned char*)os[s];
#pragma unroll
            for (int it = 0; it < 64 * A / 2048; ++it) {
                int g = (it * 256 + t) * 8;
                int row = g / A, c = g % A;
                int gn = node0 + row;
                if (gn < n)
                    *(uint2*)&og[(unsigned)gn * A + c] = *(const uint2*)&Obb[row * OROW + c];
            }
        } else {
            unsigned short* og = (unsigned short*)os[s];
#pragma unroll
            for (int it = 0; it < 64 * A / 2048; ++it) {
                int g = (it * 256 + t) * 8;
                int row = g / A, c = g % A;
                int gn = node0 + row;
                if (gn < n)
                    *(uint4*)&og[(unsigned)gn * A + c] = *(const uint4*)&Ob[row * OROW + c];
            }
        }
        __syncthreads();
    }
}

// ================= layer-0 edge helpers (fp8 k/v, f32 q regs) ==================
static __device__ __forceinline__ void edge_pair128(
    const float* qf, const uint2* __restrict__ kb, const uint2* __restrict__ vb,
    const int* __restrict__ col, int base, int t, int il, float scale,
    float& l, float* ax)
{
    unsigned d0 = (unsigned)col[base + t] * 16u + (unsigned)il;
    unsigned d1 = (unsigned)col[base + t + 4] * 16u + (unsigned)il;
    uint2 kw0 = kb[d0], kw1 = kb[d1];
    uint2 vw0 = vb[d0], vw1 = vb[d1];
    float p0 = dot8f8(qf, kw0);
    float p1 = dot8f8(qf, kw1);
    p0 += __shfl_xor(p0, 1); p0 += __shfl_xor(p0, 2);
    p1 += __shfl_xor(p1, 1); p1 += __shfl_xor(p1, 2);
    float e0 = __expf(p0 * scale);
    float e1 = __expf(p1 * scale);
    l += e0 + e1;
    acc8f8(ax, e0, vw0);
    acc8f8(ax, e1, vw1);
}
static __device__ __forceinline__ void edge_one128(
    const float* qf, const uint2* __restrict__ kb, const uint2* __restrict__ vb,
    const int* __restrict__ col, int base, int t, int il, float scale,
    float& l, float* ax)
{
    unsigned d = (unsigned)col[base + t] * 16u + (unsigned)il;
    uint2 kw = kb[d], vw = vb[d];
    float p = dot8f8(qf, kw);
    p += __shfl_xor(p, 1); p += __shfl_xor(p, 2);
    float e = __expf(p * scale);
    l += e;
    acc8f8(ax, e, vw);
}

// both layer-0 hops INTERLEAVED in one loop; ELU'd sum written once
__global__ __launch_bounds__(256) void gat2_128(
    const unsigned short* __restrict__ q0, const unsigned short* __restrict__ q1,
    const uint2* __restrict__ k0, const uint2* __restrict__ v0,
    const uint2* __restrict__ k1, const uint2* __restrict__ v1,
    const int* __restrict__ rp0, const int* __restrict__ dg0, const int* __restrict__ cl0,
    const int* __restrict__ rp1, const int* __restrict__ dg1, const int* __restrict__ cl1,
    float* __restrict__ out, float scale, int n)
{
    int wid  = (blockIdx.x * 256 + threadIdx.x) >> 6;
    int lane = threadIdx.x & 63;
    if (wid >= n) return;
    int eslot = lane >> 4, il = lane & 15;
    unsigned qoff = (unsigned)wid * 128u + (unsigned)(il * 8);

    float qf0[8], qf1[8];
    load_qf(q0 + qoff, qf0);
    load_qf(q1 + qoff, qf1);

    int s0 = rp0[wid], c0 = dg0[wid];
    int s1 = rp1[wid], c1 = dg1[wid];

    float l0 = 0.f, l1 = 0.f;
    float ax0[8], ax1[8];
#pragma unroll
    for (int j = 0; j < 8; ++j) { ax0[j] = 0.f; ax1[j] = 0.f; }

    int t0 = eslot, t1 = eslot;
    // interleaved main loop: 2 edges per hop per iteration (4 independent chains)
    while (t0 + 4 < c0 && t1 + 4 < c1) {
        edge_pair128(qf0, k0, v0, cl0, s0, t0, il, scale, l0, ax0);
        edge_pair128(qf1, k1, v1, cl1, s1, t1, il, scale, l1, ax1);
        t0 += 8; t1 += 8;
    }
    for (; t0 + 4 < c0; t0 += 8) edge_pair128(qf0, k0, v0, cl0, s0, t0, il, scale, l0, ax0);
    for (; t0 < c0;     t0 += 4) edge_one128 (qf0, k0, v0, cl0, s0, t0, il, scale, l0, ax0);
    for (; t1 + 4 < c1; t1 += 8) edge_pair128(qf1, k1, v1, cl1, s1, t1, il, scale, l1, ax1);
    for (; t1 < c1;     t1 += 4) edge_one128 (qf1, k1, v1, cl1, s1, t1, il, scale, l1, ax1);

    // fused eslot merge for both hops (18 values x 2 rounds)
#pragma unroll
    for (int off = 16; off <= 32; off <<= 1) {
        l0 += __shfl_xor(l0, off);
        l1 += __shfl_xor(l1, off);
#pragma unroll
        for (int j = 0; j < 8; ++j) {
            ax0[j] += __shfl_xor(ax0[j], off);
            ax1[j] += __shfl_xor(ax1[j], off);
        }
    }
    if (eslot == 0) {
        float inv0 = (l0 > 0.f) ? 1.f / l0 : 0.f;
        float inv1 = (l1 > 0.f) ? 0.5f / l1 : 0.f;
        float z[8];
#pragma unroll
        for (int j = 0; j < 8; ++j) z[j] = elu1(ax0[j] * inv0 + ax1[j] * inv1);
        float4* op = (float4*)(out + (unsigned)wid * 128u + (unsigned)(il * 8));
        op[0] = make_float4(z[0], z[1], z[2], z[3]);
        op[1] = make_float4(z[4], z[5], z[6], z[7]);
    }
}

// ================= layer-1 edge helper (fp8 k/v, f32 q regs) ===================
static __device__ __forceinline__ void edge_one32(
    const float* qf, const uint2* __restrict__ kb, const uint2* __restrict__ vb,
    const int* __restrict__ col, int base, int t, int il, float scale,
    float& l, float* ax)
{
    unsigned d = (unsigned)col[base + t] * 4u + (unsigned)il;
    uint2 kw = kb[d], vw = vb[d];
    float p = dot8f8(qf, kw);
    float e = __expf(p * scale);
    l += e;
    acc8f8(ax, e, vw);
}

// both layer-1 hops INTERLEAVED + fused log_softmax -> final output
__global__ __launch_bounds__(256) void gat2_32(
    const unsigned short* __restrict__ q0, const unsigned short* __restrict__ q1,
    const uint2* __restrict__ k0, const uint2* __restrict__ v0,
    const uint2* __restrict__ k1, const uint2* __restrict__ v1,
    const int* __restrict__ rp0, const int* __restrict__ dg0, const int* __restrict__ cl0,
    const int* __restrict__ rp1, const int* __restrict__ dg1, const int* __restrict__ cl1,
    float* __restrict__ outp, float scale, int n)
{
    int wid  = (blockIdx.x * 256 + threadIdx.x) >> 6;
    int lane = threadIdx.x & 63;
    if (wid >= n) return;
    int eslot = lane >> 2, il = lane & 3;
    unsigned qoff = (unsigned)wid * 32u + (unsigned)(il * 8);

    float qf0[8], qf1[8];
    load_qf(q0 + qoff, qf0);
    load_qf(q1 + qoff, qf1);

    int s0 = rp0[wid], c0 = dg0[wid];
    int s1 = rp1[wid], c1 = dg1[wid];

    float l0 = 0.f, l1 = 0.f;
    float ax0[8], ax1[8];
#pragma unroll
    for (int j = 0; j < 8; ++j) { ax0[j] = 0.f; ax1[j] = 0.f; }

    int t0 = eslot, t1 = eslot;
    while (t0 < c0 && t1 < c1) {
        edge_one32(qf0, k0, v0, cl0, s0, t0, il, scale, l0, ax0);
        edge_one32(qf1, k1, v1, cl1, s1, t1, il, scale, l1, ax1);
        t0 += 16; t1 += 16;
    }
    for (; t0 < c0; t0 += 16) edge_one32(qf0, k0, v0, cl0, s0, t0, il, scale, l0, ax0);
    for (; t1 < c1; t1 += 16) edge_one32(qf1, k1, v1, cl1, s1, t1, il, scale, l1, ax1);

    // fused eslot merge for both hops (18 values x 5 rounds, lane bits 2-5... 4..32)
#pragma unroll
    for (int off = 4; off <= 32; off <<= 1) {
        l0 += __shfl_xor(l0, off);
        l1 += __shfl_xor(l1, off);
#pragma unroll
        for (int j = 0; j < 8; ++j) {
            ax0[j] += __shfl_xor(ax0[j], off);
            ax1[j] += __shfl_xor(ax1[j], off);
        }
    }
    if (eslot == 0) {
        float inv0 = (l0 > 0.f) ? 1.f / l0 : 0.f;
        float inv1 = (l1 > 0.f) ? 0.5f / l1 : 0.f;
        float z[8];
#pragma unroll
        for (int j = 0; j < 8; ++j) z[j] = ax0[j] * inv0 + ax1[j] * inv1;
        float mx = z[0];
#pragma unroll
        for (int j = 1; j < 8; ++j) mx = fmaxf(mx, z[j]);
        mx = fmaxf(mx, __shfl_xor(mx, 1));
        mx = fmaxf(mx, __shfl_xor(mx, 2));
        float sm = 0.f;
#pragma unroll
        for (int j = 0; j < 8; ++j) sm += __expf(z[j] - mx);
        sm += __shfl_xor(sm, 1);
        sm += __shfl_xor(sm, 2);
        float lse = mx + logf(sm);
        float4* op = (float4*)(outp + (unsigned)wid * 32u + (unsigned)(il * 8));
        op[0] = make_float4(z[0] - lse, z[1] - lse, z[2] - lse, z[3] - lse);
        op[1] = make_float4(z[4] - lse, z[5] - lse, z[6] - lse, z[7] - lse);
    }
}

extern "C" void kernel_launch(void* const* d_in, const int* in_sizes, int n_in,
                              void* d_out, int out_size, void* d_ws, size_t ws_size,
                              hipStream_t stream)
{
    const float* x   = (const float*)d_in[0];
    const float* Wq0 = (const float*)d_in[1];
    const float* bq0 = (const float*)d_in[2];
    const float* Wk0 = (const float*)d_in[3];
    const float* bk0 = (const float*)d_in[4];
    const float* Wv0 = (const float*)d_in[5];
    const float* bv0 = (const float*)d_in[6];
    const float* Wq1 = (const float*)d_in[7];
    const float* bq1 = (const float*)d_in[8];
    const float* Wk1 = (const float*)d_in[9];
    const float* bk1 = (const float*)d_in[10];
    const float* Wv1 = (const float*)d_in[11];
    const float* bv1 = (const float*)d_in[12];
    const int* e0 = (const int*)d_in[13];
    const int* e1 = (const int*)d_in[14];
    const int* e2 = (const int*)d_in[15];
    const int* e3 = (const int*)d_in[16];

    char* w = (char*)d_ws;
    unsigned short* q0h = (unsigned short*)w; w += (size_t)N_NODES * HID * 2;   // 12.8 MB
    unsigned short* q1h = (unsigned short*)w; w += (size_t)N_NODES * HID * 2;   // 12.8
    unsigned char*  k0c = (unsigned char*)w;  w += (size_t)N_NODES * HID;       // 6.4
    unsigned char*  v0c = (unsigned char*)w;  w += (size_t)N_NODES * HID;
    unsigned char*  k1c = (unsigned char*)w;  w += (size_t)N_NODES * HID;
    unsigned char*  v1c = (unsigned char*)w;  w += (size_t)N_NODES * HID;
    float*          acc = (float*)w;          w += (size_t)N_NODES * HID * 4;   // 25.6
    int* deg    = (int*)w; w += (size_t)4 * N_NODES * 4;
    int* rowptr = (int*)w; w += (size_t)4 * N_NODES * 4;
    int* col    = (int*)w; w += (size_t)4 * N_EDGES * 4;
    int* bcnt   = (int*)w; w += (size_t)4 * NBUCK * 4;
    int* bbase  = (int*)w; w += (size_t)4 * (NBUCK + 1) * 4;
    int* bcur   = (int*)w; w += (size_t)4 * NBUCK * 4;
    unsigned short* wq0b = (unsigned short*)w; w += (size_t)2 * HID * IN_F * 2;
    unsigned short* wk0b = (unsigned short*)w; w += (size_t)2 * HID * IN_F * 2;
    unsigned short* wv0b = (unsigned short*)w; w += (size_t)2 * HID * IN_F * 2;
    unsigned short* wq1b = (unsigned short*)w; w += (size_t)2 * CLS * IN_F * 2;
    unsigned short* wk1b = (unsigned short*)w; w += (size_t)2 * CLS * IN_F * 2;
    unsigned short* wv1b = (unsigned short*)w; w += (size_t)2 * CLS * IN_F * 2;

    // aliases: pairs (12.8 MB) lives in q0h during CSR build (before any qkv).
    unsigned int* pairs = (unsigned int*)q0h;
    // layer-1 buffers alias q0h/q1h (dead after gat2_128):
    // q f16 (3.2 MB each), k/v fp8 (1.6 MB each)
    unsigned short* qA0 = q0h;
    unsigned short* qA1 = q0h + (size_t)N_NODES * CLS;
    unsigned char*  kA0 = (unsigned char*)(q0h + (size_t)2 * N_NODES * CLS);
    unsigned char*  vA0 = kA0 + (size_t)N_NODES * CLS;
    unsigned char*  kA1 = (unsigned char*)q1h;
    unsigned char*  vA1 = kA1 + (size_t)N_NODES * CLS;

    float* out = (float*)d_out;
    const int NB = (N_NODES + 3) / 4;
    const int QB = (N_NODES + 63) / 64;        // 782 blocks, 64 nodes each
    const float sc0 = 1.f / sqrtf(32.f), sc1 = 1.f / sqrtf(8.f);

    // ---------- weights -> bf16 (1 launch) ----------
    const int W0 = 2 * HID * IN_F, W1 = 2 * CLS * IN_F;
    conv6<<<dim3((W0 + 255) / 256, 6), 256, 0, stream>>>(
        Wq0, Wk0, Wv0, Wq1, Wk1, Wv1, wq0b, wk0b, wv0b, wq1b, wk1b, wv1b, W0, W1);

    // ---------- build 4 CSRs ----------
    hipMemsetAsync(bcnt, 0, (size_t)4 * NBUCK * 4, stream);
    bucket_hist<<<dim3(256, 4), 256, 0, stream>>>(e0, e1, e2, e3, bcnt, N_EDGES);
    bucket_scan<<<4, 256, 0, stream>>>(bcnt, bbase, bcur);
    pass1_scatter<<<dim3((N_EDGES + TILE - 1) / TILE, 4), 256, 0, stream>>>(
        e0, e1, e2, e3, bcur, pairs, N_EDGES);
    pass2_place<<<dim3(NBUCK, 4), 256, 0, stream>>>(
        pairs, bbase, rowptr, deg, col, N_EDGES, N_NODES);

    // ================= layer 0: qkv both hops (fp8 k/v), gather both hops =======
    qkv_lds<HID, true><<<QB, 256, 0, stream>>>(
        x, wq0b, bq0, wk0b, bk0, wv0b, bv0,
        q0h, q1h, k0c, k1c, v0c, v1c, N_NODES);
    gat2_128<<<NB, 256, 0, stream>>>(
        q0h, q1h,
        (const uint2*)k0c, (const uint2*)v0c, (const uint2*)k1c, (const uint2*)v1c,
        rowptr,            deg,            col,
        rowptr + N_NODES,  deg + N_NODES,  col + N_EDGES,
        acc, sc0, N_NODES);

    // ================= layer 1: qkv both hops (fp8 k/v), gather + logsoftmax ====
    qkv_lds<CLS, true><<<QB, 256, 0, stream>>>(
        acc, wq1b, bq1, wk1b, bk1, wv1b, bv1,
        qA0, qA1, kA0, kA1, vA0, vA1, N_NODES);
    gat2_32<<<NB, 256, 0, stream>>>(
        qA0, qA1,
        (const uint2*)kA0, (const uint2*)vA0, (const uint2*)kA1, (const uint2*)vA1,
        rowptr + 2 * N_NODES, deg + 2 * N_NODES, col + (size_t)2 * N_EDGES,
        rowptr + 3 * N_NODES, deg + 3 * N_NODES, col + (size_t)3 * N_EDGES,
        out, sc1, N_NODES);
}

// Round 15
// 278.530 us; speedup vs baseline: 1.0276x; 1.0276x over previous
//
#include <hip/hip_runtime.h>
#include <hip/hip_bf16.h>
#include <math.h>

#define N_NODES 50000
#define N_EDGES 800000
#define IN_F    128
#define HID     128
#define CLS     32
#define NHEAD   4
#define NBUCK   196        // ceil(N_NODES / 256)

typedef __attribute__((ext_vector_type(8))) short  short8;
typedef __attribute__((ext_vector_type(4))) float  floatx4;
typedef __attribute__((ext_vector_type(2))) float  f32x2;
typedef _Float16 h2 __attribute__((ext_vector_type(2)));

// ---------- conversions ----------
static __device__ __forceinline__ unsigned short f2bf(float f) {
    unsigned int u = __float_as_uint(f);
    return (unsigned short)((u + 0x7fffu + ((u >> 16) & 1u)) >> 16);
}
static __device__ __forceinline__ unsigned short f2h(float f) {
    return __builtin_bit_cast(unsigned short, (_Float16)f);
}
static __device__ __forceinline__ h2 uh2(unsigned int u) {
    return __builtin_bit_cast(h2, u);
}
static __device__ __forceinline__ float elu1(float x) {
    return x > 0.f ? x : expm1f(x);
}

// fp8 8-elem dot against f32 q (q pre-scaled): two chains for ILP
static __device__ __forceinline__ float dot8f8(const float* qf, unsigned kx, unsigned ky) {
    f32x2 a0 = __builtin_amdgcn_cvt_pk_f32_fp8((int)kx, false);
    f32x2 a1 = __builtin_amdgcn_cvt_pk_f32_fp8((int)kx, true);
    f32x2 a2 = __builtin_amdgcn_cvt_pk_f32_fp8((int)ky, false);
    f32x2 a3 = __builtin_amdgcn_cvt_pk_f32_fp8((int)ky, true);
    float p0 = fmaf(qf[0], a0.x, qf[1] * a0.y);
    p0 = fmaf(qf[2], a1.x, fmaf(qf[3], a1.y, p0));
    float p1 = fmaf(qf[4], a2.x, qf[5] * a2.y);
    p1 = fmaf(qf[6], a3.x, fmaf(qf[7], a3.y, p1));
    return p0 + p1;
}
static __device__ __forceinline__ void acc8f8(float* ax, float e, unsigned vx, unsigned vy) {
    f32x2 a0 = __builtin_amdgcn_cvt_pk_f32_fp8((int)vx, false);
    f32x2 a1 = __builtin_amdgcn_cvt_pk_f32_fp8((int)vx, true);
    f32x2 a2 = __builtin_amdgcn_cvt_pk_f32_fp8((int)vy, false);
    f32x2 a3 = __builtin_amdgcn_cvt_pk_f32_fp8((int)vy, true);
    ax[0] = fmaf(e, a0.x, ax[0]); ax[1] = fmaf(e, a0.y, ax[1]);
    ax[2] = fmaf(e, a1.x, ax[2]); ax[3] = fmaf(e, a1.y, ax[3]);
    ax[4] = fmaf(e, a2.x, ax[4]); ax[5] = fmaf(e, a2.y, ax[5]);
    ax[6] = fmaf(e, a3.x, ax[6]); ax[7] = fmaf(e, a3.y, ax[7]);
}
// load q (f16) into f32 regs, pre-multiplied by scale
static __device__ __forceinline__ void load_qf(const unsigned short* qp, float scale, float* qf) {
    uint4 qw = *(const uint4*)qp;
    h2 t0 = uh2(qw.x), t1 = uh2(qw.y), t2 = uh2(qw.z), t3 = uh2(qw.w);
    qf[0] = (float)t0.x * scale; qf[1] = (float)t0.y * scale;
    qf[2] = (float)t1.x * scale; qf[3] = (float)t1.y * scale;
    qf[4] = (float)t2.x * scale; qf[5] = (float)t2.y * scale;
    qf[6] = (float)t3.x * scale; qf[7] = (float)t3.y * scale;
}

// ---------- weight conversion: all 6 matrices in one launch ----------
__global__ __launch_bounds__(256) void conv6(
    const float* __restrict__ a0, const float* __restrict__ a1, const float* __restrict__ a2,
    const float* __restrict__ a3, const float* __restrict__ a4, const float* __restrict__ a5,
    unsigned short* __restrict__ o0, unsigned short* __restrict__ o1, unsigned short* __restrict__ o2,
    unsigned short* __restrict__ o3, unsigned short* __restrict__ o4, unsigned short* __restrict__ o5,
    int cBig, int cSmall)
{
    const float* srcs[6] = {a0, a1, a2, a3, a4, a5};
    unsigned short* dsts[6] = {o0, o1, o2, o3, o4, o5};
    int s = blockIdx.y;
    int count = (s < 3) ? cBig : cSmall;
    int i = blockIdx.x * 256 + threadIdx.x;
    if (i < count) dsts[s][i] = f2bf(srcs[s][i]);
}

// ================= CSR build: 2-pass coarse-bucket counting sort =================
__global__ __launch_bounds__(256) void bucket_hist(
    const int* __restrict__ e0, const int* __restrict__ e1,
    const int* __restrict__ e2, const int* __restrict__ e3,
    int* __restrict__ bcnt, int nE)
{
    const int s = blockIdx.y;
    const int* ep = (s == 0) ? e0 : (s == 1) ? e1 : (s == 2) ? e2 : e3;
    __shared__ int h[NBUCK];
    for (int i = threadIdx.x; i < NBUCK; i += 256) h[i] = 0;
    __syncthreads();
    for (int e = blockIdx.x * 256 + threadIdx.x; e < nE; e += gridDim.x * 256)
        atomicAdd(&h[ep[e] >> 8], 1);
    __syncthreads();
    for (int i = threadIdx.x; i < NBUCK; i += 256)
        if (h[i]) atomicAdd(&bcnt[s * NBUCK + i], h[i]);
}

__global__ __launch_bounds__(256) void bucket_scan(
    const int* __restrict__ bcnt, int* __restrict__ bbase, int* __restrict__ bcur)
{
    int s = blockIdx.x;
    __shared__ int tmp[256];
    int v = (threadIdx.x < NBUCK) ? bcnt[s * NBUCK + threadIdx.x] : 0;
    tmp[threadIdx.x] = v; __syncthreads();
    for (int o = 1; o < 256; o <<= 1) {
        int t = (threadIdx.x >= o) ? tmp[threadIdx.x - o] : 0;
        __syncthreads(); tmp[threadIdx.x] += t; __syncthreads();
    }
    int excl = tmp[threadIdx.x] - v;
    if (threadIdx.x < NBUCK) {
        bbase[s * (NBUCK + 1) + threadIdx.x] = excl;
        bcur[s * NBUCK + threadIdx.x] = excl;
    }
    if (threadIdx.x == NBUCK - 1)
        bbase[s * (NBUCK + 1) + NBUCK] = excl + v;
}

// pass 1: packed (src&255)<<16 | dst  (dst < 65536 since N=50000)
#define TILE 8192
__global__ __launch_bounds__(256) void pass1_scatter(
    const int* __restrict__ e0, const int* __restrict__ e1,
    const int* __restrict__ e2, const int* __restrict__ e3,
    int* __restrict__ bcur, unsigned int* __restrict__ pairs, int nE)
{
    const int s = blockIdx.y;
    const int* ep = (s == 0) ? e0 : (s == 1) ? e1 : (s == 2) ? e2 : e3;
    const int tile0 = blockIdx.x * TILE;
    __shared__ int hist[NBUCK], base[NBUCK], cur[NBUCK];
    for (int i = threadIdx.x; i < NBUCK; i += 256) { hist[i] = 0; cur[i] = 0; }
    __syncthreads();
    for (int i = threadIdx.x; i < TILE; i += 256) {
        int e = tile0 + i;
        if (e < nE) atomicAdd(&hist[ep[e] >> 8], 1);
    }
    __syncthreads();
    for (int i = threadIdx.x; i < NBUCK; i += 256)
        base[i] = hist[i] ? atomicAdd(&bcur[s * NBUCK + i], hist[i]) : 0;
    __syncthreads();
    unsigned int* pp = pairs + (size_t)s * nE;
    for (int i = threadIdx.x; i < TILE; i += 256) {
        int e = tile0 + i;
        if (e < nE) {
            int src = ep[e], dst = ep[e + nE];
            int b = src >> 8;
            int r = atomicAdd(&cur[b], 1);
            pp[base[b] + r] = ((unsigned int)(src & 255) << 16) | (unsigned int)dst;
        }
    }
}

__global__ __launch_bounds__(256) void pass2_place(
    const unsigned int* __restrict__ pairs, const int* __restrict__ bbase,
    int* __restrict__ rowptr, int* __restrict__ deg, int* __restrict__ col,
    int nE, int n)
{
    const int s = blockIdx.y, b = blockIdx.x;
    const int base0 = bbase[s * (NBUCK + 1) + b];
    const int ecnt  = bbase[s * (NBUCK + 1) + b + 1] - base0;
    const unsigned int* pp = pairs + (size_t)s * nE + base0;
    __shared__ int hist[256], cur[256];
    hist[threadIdx.x] = 0;
    __syncthreads();
    for (int i = threadIdx.x; i < ecnt; i += 256)
        atomicAdd(&hist[(pp[i] >> 16) & 255], 1);
    __syncthreads();
    int v = hist[threadIdx.x];
    cur[threadIdx.x] = v; __syncthreads();
    for (int o = 1; o < 256; o <<= 1) {
        int t = (threadIdx.x >= o) ? cur[threadIdx.x - o] : 0;
        __syncthreads(); cur[threadIdx.x] += t; __syncthreads();
    }
    int excl = cur[threadIdx.x] - v;
    int node = b * 256 + threadIdx.x;
    if (node < n) {
        rowptr[(size_t)s * n + node] = base0 + excl;
        deg[(size_t)s * n + node] = v;
    }
    __syncthreads();
    cur[threadIdx.x] = excl;
    __syncthreads();
    int* colp = col + (size_t)s * nE + base0;
    for (int i = threadIdx.x; i < ecnt; i += 256) {
        unsigned int pr = pp[i];
        int r = atomicAdd(&cur[(pr >> 16) & 255], 1);
        colp[r] = (int)(pr & 0xffffu);
    }
}

// ================= LDS-tiled MFMA Q/K/V projection ============================
// q -> f16 node-major; k/v -> INTERLEAVED fp8 kv buffer:
// per node, unit u (16B) = { k bytes [u*8, u*8+8), v bytes [u*8, u*8+8) }.
static __device__ __forceinline__ short8 pack8(const float* p) {
    float4 a = *(const float4*)p;
    float4 b = *(const float4*)(p + 4);
    short8 v;
    v[0] = (short)f2bf(a.x); v[1] = (short)f2bf(a.y);
    v[2] = (short)f2bf(a.z); v[3] = (short)f2bf(a.w);
    v[4] = (short)f2bf(b.x); v[5] = (short)f2bf(b.y);
    v[6] = (short)f2bf(b.z); v[7] = (short)f2bf(b.w);
    return v;
}

template<int A>
__global__ __launch_bounds__(256) void qkv_lds(
    const float* __restrict__ x,
    const unsigned short* __restrict__ Wq, const float* __restrict__ bq,
    const unsigned short* __restrict__ Wk, const float* __restrict__ bk,
    const unsigned short* __restrict__ Wv, const float* __restrict__ bv,
    unsigned short* __restrict__ q0, unsigned short* __restrict__ q1,
    unsigned char* __restrict__ kv0, unsigned char* __restrict__ kv1,
    int n)
{
    constexpr int NT   = A / 16;
    constexpr int WROW = IN_F + 8;
    constexpr int OROW = A + 8;
    __shared__ unsigned short Wb[A * WROW];
    __shared__ unsigned short Ob[64 * OROW];

    const int t    = threadIdx.x;
    const int wave = t >> 6;
    const int lane = t & 63;
    const int r    = lane & 15;
    const int kg   = lane >> 4;
    const int node0 = blockIdx.x * 64;
    const int myrow = wave * 16 + r;
    const int xnode = min(node0 + myrow, n - 1);

    short8 xf[4];
    const float* xr = x + (unsigned)xnode * IN_F + kg * 8;
#pragma unroll
    for (int ks = 0; ks < 4; ++ks) xf[ks] = pack8(xr + ks * 32);

    const size_t off = (size_t)A * IN_F;
    const unsigned short* Ws[6] = {Wq, Wk, Wv, Wq + off, Wk + off, Wv + off};
    const float*          bs[6] = {bq, bk, bv, bq + A, bk + A, bv + A};

    for (int s = 0; s < 6; ++s) {
        const unsigned short* Wg = Ws[s];
#pragma unroll
        for (int it = 0; it < A * IN_F / 2048; ++it) {
            int e = (it * 256 + t) * 8;
            int row = e / IN_F, c = e % IN_F;
            *(uint4*)&Wb[row * WROW + c] = *(const uint4*)&Wg[e];
        }
        __syncthreads();

        floatx4 acc[NT];
        const float* b = bs[s];
#pragma unroll
        for (int nt = 0; nt < NT; ++nt) {
            float4 b4 = *(const float4*)(b + nt * 16 + kg * 4);
            acc[nt] = (floatx4){b4.x, b4.y, b4.z, b4.w};
        }
#pragma unroll
        for (int ks = 0; ks < 4; ++ks) {
#pragma unroll
            for (int nt = 0; nt < NT; ++nt) {
                short8 wf = *(const short8*)&Wb[(nt * 16 + r) * WROW + ks * 32 + kg * 8];
                acc[nt] = __builtin_amdgcn_mfma_f32_16x16x32_bf16(wf, xf[ks], acc[nt], 0, 0, 0);
            }
        }

        const bool isQ = (s == 0) || (s == 3);
        if (!isQ) {
            unsigned char* Obb = (unsigned char*)Ob;
#pragma unroll
            for (int nt = 0; nt < NT; ++nt) {
                int p = __builtin_amdgcn_cvt_pk_fp8_f32(acc[nt][0], acc[nt][1], 0, false);
                p     = __builtin_amdgcn_cvt_pk_fp8_f32(acc[nt][2], acc[nt][3], p, true);
                *(unsigned int*)&Obb[myrow * OROW + nt * 16 + kg * 4] = (unsigned int)p;
            }
        } else {
#pragma unroll
            for (int nt = 0; nt < NT; ++nt) {
                unsigned int lo = (unsigned int)f2h(acc[nt][0]) | ((unsigned int)f2h(acc[nt][1]) << 16);
                unsigned int hi = (unsigned int)f2h(acc[nt][2]) | ((unsigned int)f2h(acc[nt][3]) << 16);
                *(uint2*)&Ob[myrow * OROW + nt * 16 + kg * 4] = make_uint2(lo, hi);
            }
        }
        __syncthreads();

        if (!isQ) {
            // store fp8 halves into interleaved kv buffer: unit (c>>3)*16 + voff
            const unsigned char* Obb = (const unsigned char*)Ob;
            unsigned char* og = (s < 3) ? kv0 : kv1;
            const unsigned voff = (s == 2 || s == 5) ? 8u : 0u;
#pragma unroll
            for (int it = 0; it < 64 * A / 2048; ++it) {
                int g = (it * 256 + t) * 8;
                int row = g / A, c = g % A;
                int gn = node0 + row;
                if (gn < n)
                    *(uint2*)&og[(unsigned)gn * (2 * A) + ((unsigned)(c >> 3) << 4) + voff] =
                        *(const uint2*)&Obb[row * OROW + c];
            }
        } else {
            unsigned short* og = (s == 0) ? q0 : q1;
#pragma unroll
            for (int it = 0; it < 64 * A / 2048; ++it) {
                int g = (it * 256 + t) * 8;
                int row = g / A, c = g % A;
                int gn = node0 + row;
                if (gn < n)
                    *(uint4*)&og[(unsigned)gn * A + c] = *(const uint4*)&Ob[row * OROW + c];
            }
        }
        __syncthreads();
    }
}

// ================= layer-0 gather phase: interleaved fp8 kv, scaled f32 q ======
// eslot = lane>>4 (4 eslots, 2x unroll = 8 edges in flight/wave),
// il = lane&15 -> one 16B kv unit (k8+v8); head-group = 4 lanes (shfl 1,2).
__device__ __forceinline__ void gat_phase128(
    const unsigned short* __restrict__ q, const uint4* __restrict__ kvb,
    const int* __restrict__ rowptr, const int* __restrict__ deg,
    const int* __restrict__ col,
    int wid, int eslot, int il, float scale, float* r)
{
    float qf[8];
    load_qf(q + (unsigned)wid * 128u + (unsigned)(il * 8), scale, qf);
    int start = rowptr[wid], cnt = deg[wid];
    float l = 0.f;
    float ax[8];
#pragma unroll
    for (int j = 0; j < 8; ++j) ax[j] = 0.f;

    int t = eslot;
    for (; t + 4 < cnt; t += 8) {
        unsigned d0 = (unsigned)col[start + t] * 16u + (unsigned)il;
        unsigned d1 = (unsigned)col[start + t + 4] * 16u + (unsigned)il;
        uint4 kv0 = kvb[d0];
        uint4 kv1 = kvb[d1];
        float p0 = dot8f8(qf, kv0.x, kv0.y);
        float p1 = dot8f8(qf, kv1.x, kv1.y);
        p0 += __shfl_xor(p0, 1); p0 += __shfl_xor(p0, 2);
        p1 += __shfl_xor(p1, 1); p1 += __shfl_xor(p1, 2);
        float e0 = __expf(p0);
        float e1 = __expf(p1);
        l += e0 + e1;
        acc8f8(ax, e0, kv0.z, kv0.w);
        acc8f8(ax, e1, kv1.z, kv1.w);
    }
    for (; t < cnt; t += 4) {
        unsigned d = (unsigned)col[start + t] * 16u + (unsigned)il;
        uint4 kv = kvb[d];
        float p = dot8f8(qf, kv.x, kv.y);
        p += __shfl_xor(p, 1); p += __shfl_xor(p, 2);
        float e = __expf(p);
        l += e;
        acc8f8(ax, e, kv.z, kv.w);
    }
#pragma unroll
    for (int off = 16; off <= 32; off <<= 1) {
        l += __shfl_xor(l, off);
#pragma unroll
        for (int j = 0; j < 8; ++j) ax[j] += __shfl_xor(ax[j], off);
    }
    float inv = (l > 0.f) ? 1.f / l : 0.f;
#pragma unroll
    for (int j = 0; j < 8; ++j) r[j] = ax[j] * inv;
}

// both layer-0 hops; ELU'd sum written once (f32 node-major for layer-1 input)
__global__ __launch_bounds__(256) void gat2_128(
    const unsigned short* __restrict__ q0, const unsigned short* __restrict__ q1,
    const uint4* __restrict__ kv0, const uint4* __restrict__ kv1,
    const int* __restrict__ rp0, const int* __restrict__ dg0, const int* __restrict__ cl0,
    const int* __restrict__ rp1, const int* __restrict__ dg1, const int* __restrict__ cl1,
    float* __restrict__ out, float scale, int n)
{
    int wid  = (blockIdx.x * 256 + threadIdx.x) >> 6;
    int lane = threadIdx.x & 63;
    if (wid >= n) return;
    int eslot = lane >> 4, il = lane & 15;

    float r0[8], r1[8];
    gat_phase128(q0, kv0, rp0, dg0, cl0, wid, eslot, il, scale, r0);
    gat_phase128(q1, kv1, rp1, dg1, cl1, wid, eslot, il, scale, r1);

    if (eslot == 0) {
        float z[8];
#pragma unroll
        for (int j = 0; j < 8; ++j) z[j] = elu1(r0[j] + 0.5f * r1[j]);
        float4* op = (float4*)(out + (unsigned)wid * 128u + (unsigned)(il * 8));
        op[0] = make_float4(z[0], z[1], z[2], z[3]);
        op[1] = make_float4(z[4], z[5], z[6], z[7]);
    }
}

// ================= layer-1 gather phase: interleaved fp8 kv ====================
// eslot = lane>>2 (16 edges in flight), il = lane&3 = head; full head per unit.
__device__ __forceinline__ void gat_phase32(
    const unsigned short* __restrict__ q, const uint4* __restrict__ kvb,
    const int* __restrict__ rowptr, const int* __restrict__ deg,
    const int* __restrict__ col,
    int wid, int eslot, int il, float scale, float* r)
{
    float qf[8];
    load_qf(q + (unsigned)wid * 32u + (unsigned)(il * 8), scale, qf);
    int start = rowptr[wid], cnt = deg[wid];
    float l = 0.f;
    float ax[8];
#pragma unroll
    for (int j = 0; j < 8; ++j) ax[j] = 0.f;

    for (int t = eslot; t < cnt; t += 16) {
        unsigned d = (unsigned)col[start + t] * 4u + (unsigned)il;
        uint4 kv = kvb[d];
        float p = dot8f8(qf, kv.x, kv.y);
        float e = __expf(p);
        l += e;
        acc8f8(ax, e, kv.z, kv.w);
    }
#pragma unroll
    for (int off = 4; off <= 32; off <<= 1) {
        l += __shfl_xor(l, off);
#pragma unroll
        for (int j = 0; j < 8; ++j) ax[j] += __shfl_xor(ax[j], off);
    }
    float inv = (l > 0.f) ? 1.f / l : 0.f;
#pragma unroll
    for (int j = 0; j < 8; ++j) r[j] = ax[j] * inv;
}

// both layer-1 hops + fused log_softmax -> final output
__global__ __launch_bounds__(256) void gat2_32(
    const unsigned short* __restrict__ q0, const unsigned short* __restrict__ q1,
    const uint4* __restrict__ kv0, const uint4* __restrict__ kv1,
    const int* __restrict__ rp0, const int* __restrict__ dg0, const int* __restrict__ cl0,
    const int* __restrict__ rp1, const int* __restrict__ dg1, const int* __restrict__ cl1,
    float* __restrict__ outp, float scale, int n)
{
    int wid  = (blockIdx.x * 256 + threadIdx.x) >> 6;
    int lane = threadIdx.x & 63;
    if (wid >= n) return;
    int eslot = lane >> 2, il = lane & 3;

    float r0[8], r1[8];
    gat_phase32(q0, kv0, rp0, dg0, cl0, wid, eslot, il, scale, r0);
    gat_phase32(q1, kv1, rp1, dg1, cl1, wid, eslot, il, scale, r1);

    if (eslot == 0) {
        float z[8];
#pragma unroll
        for (int j = 0; j < 8; ++j) z[j] = r0[j] + 0.5f * r1[j];
        float mx = z[0];
#pragma unroll
        for (int j = 1; j < 8; ++j) mx = fmaxf(mx, z[j]);
        mx = fmaxf(mx, __shfl_xor(mx, 1));
        mx = fmaxf(mx, __shfl_xor(mx, 2));
        float sm = 0.f;
#pragma unroll
        for (int j = 0; j < 8; ++j) sm += __expf(z[j] - mx);
        sm += __shfl_xor(sm, 1);
        sm += __shfl_xor(sm, 2);
        float lse = mx + logf(sm);
        float4* op = (float4*)(outp + (unsigned)wid * 32u + (unsigned)(il * 8));
        op[0] = make_float4(z[0] - lse, z[1] - lse, z[2] - lse, z[3] - lse);
        op[1] = make_float4(z[4] - lse, z[5] - lse, z[6] - lse, z[7] - lse);
    }
}

extern "C" void kernel_launch(void* const* d_in, const int* in_sizes, int n_in,
                              void* d_out, int out_size, void* d_ws, size_t ws_size,
                              hipStream_t stream)
{
    const float* x   = (const float*)d_in[0];
    const float* Wq0 = (const float*)d_in[1];
    const float* bq0 = (const float*)d_in[2];
    const float* Wk0 = (const float*)d_in[3];
    const float* bk0 = (const float*)d_in[4];
    const float* Wv0 = (const float*)d_in[5];
    const float* bv0 = (const float*)d_in[6];
    const float* Wq1 = (const float*)d_in[7];
    const float* bq1 = (const float*)d_in[8];
    const float* Wk1 = (const float*)d_in[9];
    const float* bk1 = (const float*)d_in[10];
    const float* Wv1 = (const float*)d_in[11];
    const float* bv1 = (const float*)d_in[12];
    const int* e0 = (const int*)d_in[13];
    const int* e1 = (const int*)d_in[14];
    const int* e2 = (const int*)d_in[15];
    const int* e3 = (const int*)d_in[16];

    char* w = (char*)d_ws;
    unsigned short* q0h = (unsigned short*)w; w += (size_t)N_NODES * HID * 2;   // 12.8 MB
    unsigned short* q1h = (unsigned short*)w; w += (size_t)N_NODES * HID * 2;   // 12.8
    unsigned char*  kv0c = (unsigned char*)w; w += (size_t)N_NODES * HID * 2;   // 12.8 (interleaved k+v fp8)
    unsigned char*  kv1c = (unsigned char*)w; w += (size_t)N_NODES * HID * 2;   // 12.8
    float*          acc = (float*)w;          w += (size_t)N_NODES * HID * 4;   // 25.6
    int* deg    = (int*)w; w += (size_t)4 * N_NODES * 4;
    int* rowptr = (int*)w; w += (size_t)4 * N_NODES * 4;
    int* col    = (int*)w; w += (size_t)4 * N_EDGES * 4;
    int* bcnt   = (int*)w; w += (size_t)4 * NBUCK * 4;
    int* bbase  = (int*)w; w += (size_t)4 * (NBUCK + 1) * 4;
    int* bcur   = (int*)w; w += (size_t)4 * NBUCK * 4;
    unsigned short* wq0b = (unsigned short*)w; w += (size_t)2 * HID * IN_F * 2;
    unsigned short* wk0b = (unsigned short*)w; w += (size_t)2 * HID * IN_F * 2;
    unsigned short* wv0b = (unsigned short*)w; w += (size_t)2 * HID * IN_F * 2;
    unsigned short* wq1b = (unsigned short*)w; w += (size_t)2 * CLS * IN_F * 2;
    unsigned short* wk1b = (unsigned short*)w; w += (size_t)2 * CLS * IN_F * 2;
    unsigned short* wv1b = (unsigned short*)w; w += (size_t)2 * CLS * IN_F * 2;

    // aliases: pairs (12.8 MB) lives in q0h during CSR build (before any qkv).
    unsigned int* pairs = (unsigned int*)q0h;
    // layer-1 buffers alias q0h/q1h (dead after gat2_128):
    // qA0/qA1 f16 (3.2 MB each) in q0h; kvA0/kvA1 fp8 interleaved (3.2 MB each) in q1h
    unsigned short* qA0 = q0h;
    unsigned short* qA1 = q0h + (size_t)N_NODES * CLS;
    unsigned char*  kvA0 = (unsigned char*)q1h;
    unsigned char*  kvA1 = kvA0 + (size_t)N_NODES * CLS * 2;

    float* out = (float*)d_out;
    const int NB = (N_NODES + 3) / 4;
    const int QB = (N_NODES + 63) / 64;        // 782 blocks, 64 nodes each
    const float sc0 = 1.f / sqrtf(32.f), sc1 = 1.f / sqrtf(8.f);

    // ---------- weights -> bf16 (1 launch) ----------
    const int W0 = 2 * HID * IN_F, W1 = 2 * CLS * IN_F;
    conv6<<<dim3((W0 + 255) / 256, 6), 256, 0, stream>>>(
        Wq0, Wk0, Wv0, Wq1, Wk1, Wv1, wq0b, wk0b, wv0b, wq1b, wk1b, wv1b, W0, W1);

    // ---------- build 4 CSRs ----------
    hipMemsetAsync(bcnt, 0, (size_t)4 * NBUCK * 4, stream);
    bucket_hist<<<dim3(256, 4), 256, 0, stream>>>(e0, e1, e2, e3, bcnt, N_EDGES);
    bucket_scan<<<4, 256, 0, stream>>>(bcnt, bbase, bcur);
    pass1_scatter<<<dim3((N_EDGES + TILE - 1) / TILE, 4), 256, 0, stream>>>(
        e0, e1, e2, e3, bcur, pairs, N_EDGES);
    pass2_place<<<dim3(NBUCK, 4), 256, 0, stream>>>(
        pairs, bbase, rowptr, deg, col, N_EDGES, N_NODES);

    // ================= layer 0: qkv both hops (interleaved fp8 kv), gather =======
    qkv_lds<HID><<<QB, 256, 0, stream>>>(
        x, wq0b, bq0, wk0b, bk0, wv0b, bv0,
        q0h, q1h, kv0c, kv1c, N_NODES);
    gat2_128<<<NB, 256, 0, stream>>>(
        q0h, q1h,
        (const uint4*)kv0c, (const uint4*)kv1c,
        rowptr,            deg,            col,
        rowptr + N_NODES,  deg + N_NODES,  col + N_EDGES,
        acc, sc0, N_NODES);

    // ================= layer 1: qkv both hops (interleaved fp8 kv), gather+lsm ===
    qkv_lds<CLS><<<QB, 256, 0, stream>>>(
        acc, wq1b, bq1, wk1b, bk1, wv1b, bv1,
        qA0, qA1, kvA0, kvA1, N_NODES);
    gat2_32<<<NB, 256, 0, stream>>>(
        qA0, qA1,
        (const uint4*)kvA0, (const uint4*)kvA1,
        rowptr + 2 * N_NODES, deg + 2 * N_NODES, col + (size_t)2 * N_EDGES,
        rowptr + 3 * N_NODES, deg + 3 * N_NODES, col + (size_t)3 * N_EDGES,
        out, sc1, N_NODES);
}